// Round 1
// baseline (134730.615 us; speedup 1.0000x reference)
//
#include <hip/hip_runtime.h>

// ELMo 2-layer LSTM-with-projection, persistent kernel for MI355X (gfx950).
// B=32, T=1024, H=512(=input), CELL=4096, gates=16384, K(fused)=1024.
//
// Decomposition: 256 WGs (1/CU) x 256 thr (4 waves). Batch split into two
// halves of 16; WG g: half hg=g>>7, wgi=g&127 owns 32 cells (cb=wgi*32),
// i.e. 128 gate rows (4 gates x 32 cells), wave w handles gate w (M=32 rows).
// Gate weights [Wi;Ws] are bf16 MFMA A-fragments held in VGPRs for the whole
// layer (64 x bf16x8 = 256 VGPRs/lane). Per step: stage [x_t;h] to LDS,
// 64 MFMAs/wave, LDS gate exchange, elementwise (c-state in LDS), partial
// projection with register-resident Wp slice, partials->global, grid barrier,
// 128-way reduce (WG owns 4 h-cols), clip/mask/write, grid barrier.
// Layer-1 out stored fp32 in d_out; layer 2 reads it and adds residual.

#define TT 1024
#define HH 512
#define CC 4096

typedef __bf16 bf16_t;
typedef __attribute__((ext_vector_type(8))) __bf16 bf16x8;
typedef __attribute__((ext_vector_type(4))) __bf16 bf16x4;
typedef __attribute__((ext_vector_type(4))) float f32x4;

#define OUT_FH 16777216u          // 32*1024*512
#define OUT_FC 16809984u          // + 2*32*512

__device__ __forceinline__ float fsigm(float x) { return 1.0f / (1.0f + __expf(-x)); }
__device__ __forceinline__ float ftanh(float x) {
  x = fminf(fmaxf(x, -15.f), 15.f);
  float e = __expf(2.f * x);
  return (e - 1.f) / (e + 1.f);
}

// Monotonic-counter grid barrier. AGENT-scope acq_rel RMW forces XCD-L2
// writeback (release) and L1/L2 invalidate (acquire) -> cross-XCD coherent.
__device__ __forceinline__ void gridbar(unsigned* cnt, unsigned target) {
  __syncthreads();                 // emits s_waitcnt vmcnt(0): stores complete
  if (threadIdx.x == 0) {
    __hip_atomic_fetch_add(cnt, 1u, __ATOMIC_ACQ_REL, __HIP_MEMORY_SCOPE_AGENT);
    while (__hip_atomic_load(cnt, __ATOMIC_ACQUIRE, __HIP_MEMORY_SCOPE_AGENT) < target)
      __builtin_amdgcn_s_sleep(2);
  }
  __syncthreads();
}

__global__ void prep(const int* __restrict__ mask, int* __restrict__ len,
                     unsigned* __restrict__ cnt) {
  const int b = blockIdx.x, tid = threadIdx.x;
  int s = 0;
  for (int i = tid; i < TT; i += 256) s += mask[b * TT + i];
  __shared__ int r[256];
  r[tid] = s; __syncthreads();
  for (int st = 128; st > 0; st >>= 1) {
    if (tid < st) r[tid] += r[tid + st];
    __syncthreads();
  }
  if (tid == 0) { len[b] = r[0]; if (b == 0) *cnt = 0u; }
}

__global__ __launch_bounds__(256, 1) void elmo_lstm(
    const float* __restrict__ xin,
    const float* __restrict__ Wi_g, const float* __restrict__ Ws_g,
    const float* __restrict__ bs_g, const float* __restrict__ Wp_g,
    float* __restrict__ out,
    unsigned* __restrict__ cnt, const int* __restrict__ len_g,
    bf16_t* __restrict__ P, bf16_t* __restrict__ hbuf) {
  const int g    = blockIdx.x;
  const int tid  = threadIdx.x;
  const int hg   = g >> 7;        // batch half (0/1)
  const int wgi  = g & 127;
  const int cb   = wgi * 32;      // cell base
  const int wv   = tid >> 6;      // wave = gate index
  const int lane = tid & 63;
  const int lm   = lane & 15;
  const int lq   = lane >> 4;
  const int pb   = wgi * 4;       // owned h-column base (reduce phase)

  __shared__ bf16_t xh[16][1032];      // [n][k], stride 1032 (16B aligned rows)
  __shared__ float  gbuf[4][32][17];   // [gate][cell][n]
  __shared__ float  cbuf[32][17];      // persistent c-state [cell][n]
  __shared__ bf16_t abuf[16][48];      // act [n][cell]
  __shared__ bf16_t pbuf[512][16];     // partial h [p][n]
  __shared__ float  rbuf[64][5];
  __shared__ int    lenl[16];

  if (tid < 16) lenl[tid] = len_g[hg * 16 + tid];

  unsigned bark = 0;

#pragma unroll 1
  for (int l = 0; l < 2; ++l) {
    const float* WiL = Wi_g + (size_t)l * CC * 4 * HH;
    const float* WsL = Ws_g + (size_t)l * CC * 4 * HH;
    const float* bsL = bs_g + (size_t)l * CC * 4;
    const float* WpL = Wp_g + (size_t)l * HH * CC;

    // ---- layer init: weights -> registers (A-fragments) ----
    bf16x8 wfrag[64];                 // [mt*32+ks]; 256 VGPRs
#pragma unroll
    for (int mt = 0; mt < 2; ++mt) {
      const int row = wv * 4096 + cb + mt * 16 + lm;
#pragma unroll
      for (int ks = 0; ks < 32; ++ks) {
        const int k = ks * 32 + lq * 8;
        const float* src = (k < HH) ? (WiL + (size_t)row * HH + k)
                                    : (WsL + (size_t)row * HH + (k - HH));
        float4 a = ((const float4*)src)[0];
        float4 b = ((const float4*)src)[1];
        bf16x8 f;
        f[0] = (bf16_t)a.x; f[1] = (bf16_t)a.y; f[2] = (bf16_t)a.z; f[3] = (bf16_t)a.w;
        f[4] = (bf16_t)b.x; f[5] = (bf16_t)b.y; f[6] = (bf16_t)b.z; f[7] = (bf16_t)b.w;
        wfrag[mt * 32 + ks] = f;
      }
    }
    float biasv[8];
#pragma unroll
    for (int mt = 0; mt < 2; ++mt)
#pragma unroll
      for (int r = 0; r < 4; ++r)
        biasv[mt * 4 + r] = bsL[wv * 4096 + cb + mt * 16 + lq * 4 + r];

    bf16x8 pfrag[8];                  // Wp slice: rows wv*128+pt*16+lm, cols cb+lq*8..
#pragma unroll
    for (int pt = 0; pt < 8; ++pt) {
      const float* src = WpL + (size_t)(wv * 128 + pt * 16 + lm) * CC + cb + lq * 8;
      float4 a = ((const float4*)src)[0];
      float4 b = ((const float4*)src)[1];
      bf16x8 f;
      f[0] = (bf16_t)a.x; f[1] = (bf16_t)a.y; f[2] = (bf16_t)a.z; f[3] = (bf16_t)a.w;
      f[4] = (bf16_t)b.x; f[5] = (bf16_t)b.y; f[6] = (bf16_t)b.z; f[7] = (bf16_t)b.w;
      pfrag[pt] = f;
    }

    for (int i = tid; i < 32 * 17; i += 256) (&cbuf[0][0])[i] = 0.f;
    if (tid < 64) {                   // zero owned h slice
      int p = pb + (tid >> 4), n = tid & 15;
      hbuf[(size_t)(hg * 16 + n) * HH + p] = (bf16_t)0.f;
    }
    gridbar(cnt, 256u * (++bark));

    const float* xsrc = (l == 0) ? xin : out;   // layer2 input = layer1 out (fp32 in d_out)

#pragma unroll 1
    for (int t = 0; t < TT; ++t) {
      // ---- stage [x_t ; h_{t-1}] into LDS as bf16 ----
      {
        const int n = tid >> 4;
        const int co = (tid & 15) * 32;
        const float* xs = xsrc + ((size_t)(hg * 16 + n) * TT + t) * HH + co;
#pragma unroll
        for (int i = 0; i < 8; ++i) {
          float4 v = ((const float4*)xs)[i];
          bf16x4 pv = { (bf16_t)v.x, (bf16_t)v.y, (bf16_t)v.z, (bf16_t)v.w };
          *(bf16x4*)&xh[n][co + i * 4] = pv;
        }
        const int4* hs = (const int4*)(hbuf + (size_t)(hg * 16 + n) * HH + co);
#pragma unroll
        for (int i = 0; i < 4; ++i)
          *(int4*)&xh[n][HH + co + i * 8] = hs[i];
      }
      __syncthreads();

      // ---- gate GEMM: 64 MFMAs, weights from registers ----
      f32x4 acc0 = { biasv[0], biasv[1], biasv[2], biasv[3] };
      f32x4 acc1 = { biasv[4], biasv[5], biasv[6], biasv[7] };
#pragma unroll
      for (int ks = 0; ks < 32; ++ks) {
        bf16x8 bfr = *(const bf16x8*)&xh[lm][ks * 32 + lq * 8];
        acc0 = __builtin_amdgcn_mfma_f32_16x16x32_bf16(wfrag[ks],      bfr, acc0, 0, 0, 0);
        acc1 = __builtin_amdgcn_mfma_f32_16x16x32_bf16(wfrag[32 + ks], bfr, acc1, 0, 0, 0);
      }
#pragma unroll
      for (int r = 0; r < 4; ++r) {
        gbuf[wv][lq * 4 + r][lm]      = acc0[r];
        gbuf[wv][16 + lq * 4 + r][lm] = acc1[r];
      }
      __syncthreads();

      // ---- elementwise LSTM cell (2 (cell,n) pairs / thread) ----
#pragma unroll
      for (int e = 0; e < 2; ++e) {
        const int pp = tid * 2 + e;
        const int cell = pp >> 4, n = pp & 15;
        float ig = gbuf[0][cell][n], fg = gbuf[1][cell][n];
        float mg = gbuf[2][cell][n], og = gbuf[3][cell][n];
        float iv = fsigm(ig), fv = fsigm(fg), gv = ftanh(mg), ov = fsigm(og);
        float cp = cbuf[cell][n];
        float c  = fminf(fmaxf(iv * gv + fv * cp, -3.f), 3.f);
        const bool valid = t < lenl[n];
        float cn = valid ? c : cp;
        cbuf[cell][n] = cn;
        abuf[n][cell] = (bf16_t)(ov * ftanh(c));
        if (t == lenl[n] - 1)
          out[OUT_FC + ((size_t)(l * 32 + hg * 16 + n)) * CC + cb + cell] = cn;
      }
      __syncthreads();

      // ---- partial projection over own 32 cells ----
      {
        bf16x8 bfr = *(const bf16x8*)&abuf[lm][lq * 8];
#pragma unroll
        for (int pt = 0; pt < 8; ++pt) {
          f32x4 pa = { 0.f, 0.f, 0.f, 0.f };
          pa = __builtin_amdgcn_mfma_f32_16x16x32_bf16(pfrag[pt], bfr, pa, 0, 0, 0);
#pragma unroll
          for (int r = 0; r < 4; ++r)
            pbuf[wv * 128 + pt * 16 + lq * 4 + r][lm] = (bf16_t)pa[r];
        }
      }
      __syncthreads();
      {
        const int4* sp = (const int4*)(&pbuf[0][0]);
        int4* dp = (int4*)(P + (size_t)(hg * 128 + wgi) * (512 * 16));
#pragma unroll
        for (int i = 0; i < 4; ++i)
          dp[tid + 256 * i] = sp[tid + 256 * i];
      }
      gridbar(cnt, 256u * (++bark));

      // ---- reduce 128 partials for owned 4 h-columns ----
      {
        const int s = tid >> 6, o = tid & 63;
        const int p = pb + (o >> 4), n = o & 15;
        float sum = 0.f;
#pragma unroll 8
        for (int w2 = s * 32; w2 < s * 32 + 32; ++w2)
          sum += (float)P[((size_t)(hg * 128 + w2) * 512 + p) * 16 + n];
        rbuf[o][s] = sum;
      }
      __syncthreads();
      if (tid < 64) {
        const int o = tid;
        const int p = pb + (o >> 4), n = o & 15;
        const int b = hg * 16 + n;
        float h = rbuf[o][0] + rbuf[o][1] + rbuf[o][2] + rbuf[o][3];
        h = fminf(fmaxf(h, -3.f), 3.f);
        const bool valid = t < lenl[n];
        float hp = (float)hbuf[(size_t)b * HH + p];
        float hn = valid ? h : hp;
        hbuf[(size_t)b * HH + p] = (bf16_t)hn;
        float outv = valid ? h : 0.f;
        size_t oi = ((size_t)b * TT + t) * HH + p;
        if (l == 0) out[oi] = outv;      // layer-1 sequence (read back as layer-2 input)
        else        out[oi] += outv;     // residual: returned = l2_out + l1_out
        if (t == lenl[n] - 1)
          out[OUT_FH + ((size_t)(l * 32 + b)) * HH + p] = hn;
      }
      gridbar(cnt, 256u * (++bark));
    }
  }
}

extern "C" void kernel_launch(void* const* d_in, const int* in_sizes, int n_in,
                              void* d_out, int out_size, void* d_ws, size_t ws_size,
                              hipStream_t stream) {
  const float* xin = (const float*)d_in[0];
  const int*   mask = (const int*)d_in[1];
  const float* Wi  = (const float*)d_in[2];
  const float* Ws  = (const float*)d_in[3];
  const float* bs  = (const float*)d_in[4];
  const float* Wp  = (const float*)d_in[5];
  float* out = (float*)d_out;
  char* ws = (char*)d_ws;

  unsigned* cnt = (unsigned*)(ws);
  int* len      = (int*)(ws + 64);
  bf16_t* P    = (bf16_t*)(ws + 1024);                       // 2*128*512*16 bf16 = 4 MB
  bf16_t* hbuf = (bf16_t*)(ws + 1024 + (size_t)2 * 128 * 512 * 16 * 2);

  prep<<<32, 256, 0, stream>>>(mask, len, cnt);
  elmo_lstm<<<256, 256, 0, stream>>>(xin, Wi, Ws, bs, Wp, out, cnt, len, P, hbuf);
}

// Round 2
// 106556.470 us; speedup vs baseline: 1.2644x; 1.2644x over previous
//
#include <hip/hip_runtime.h>

// ELMo 2-layer LSTM-with-projection, persistent kernel for MI355X (gfx950).
// B=32, T=1024, H=512(=input), CELL=4096, gates=16384, K(fused)=1024.
//
// Decomposition: 256 WGs (1/CU) x 256 thr (4 waves). Batch split into two
// halves of 16; WG g: half hg=g>>7, wgi=g&127 owns 32 cells (cb=wgi*32),
// i.e. 128 gate rows (4 gates x 32 cells), wave w handles gate w (M=32 rows).
// Gate weights [Wi;Ws] are bf16 MFMA A-fragments held in VGPRs for the whole
// layer (64 x bf16x8 = 256 VGPRs/lane). Per step: stage [x_t;h] to LDS,
// 64 MFMAs/wave, LDS gate exchange, elementwise (c-state in LDS), partial
// projection with register-resident Wp slice, partials->global, grid barrier,
// 128-way reduce (WG owns 4 h-cols), clip/mask/write, grid barrier.
// Layer-1 out stored fp32 in d_out; layer 2 reads it and adds residual.
//
// R2: barrier rebuilt — fences hoisted out of the spin. The R1 barrier's
// acquire-load poll emitted buffer_inv (L1+L2 invalidate) EVERY iteration
// from 256 spinners -> invalidate storm -> ~60us/step idle (MfmaUtil 0.7%).
// Now: one release fence before arrival, relaxed add, relaxed sc1 polls,
// one acquire fence after.

#define TT 1024
#define HH 512
#define CC 4096

typedef __bf16 bf16_t;
typedef __attribute__((ext_vector_type(8))) __bf16 bf16x8;
typedef __attribute__((ext_vector_type(4))) __bf16 bf16x4;
typedef __attribute__((ext_vector_type(4))) float f32x4;

#define OUT_FH 16777216u          // 32*1024*512
#define OUT_FC 16809984u          // + 2*32*512

__device__ __forceinline__ float fsigm(float x) { return 1.0f / (1.0f + __expf(-x)); }
__device__ __forceinline__ float ftanh(float x) {
  x = fminf(fmaxf(x, -15.f), 15.f);
  float e = __expf(2.f * x);
  return (e - 1.f) / (e + 1.f);
}

// Monotonic-counter grid barrier. Release fence (one L2 writeback) before
// arrival; RELAXED fetch_add (remote-executed at coherence point); RELAXED
// sc1 polls (no invalidates); single acquire fence after the spin.
__device__ __forceinline__ void gridbar(unsigned* cnt, unsigned target) {
  __syncthreads();                 // all waves' stores issued (vmcnt drained)
  if (threadIdx.x == 0) {
    __builtin_amdgcn_fence(__ATOMIC_RELEASE, "agent");
    __hip_atomic_fetch_add(cnt, 1u, __ATOMIC_RELAXED, __HIP_MEMORY_SCOPE_AGENT);
    while (__hip_atomic_load(cnt, __ATOMIC_RELAXED, __HIP_MEMORY_SCOPE_AGENT) < target)
      __builtin_amdgcn_s_sleep(2);
    __builtin_amdgcn_fence(__ATOMIC_ACQUIRE, "agent");
  }
  __syncthreads();
}

__global__ void prep(const int* __restrict__ mask, int* __restrict__ len,
                     unsigned* __restrict__ cnt) {
  const int b = blockIdx.x, tid = threadIdx.x;
  int s = 0;
  for (int i = tid; i < TT; i += 256) s += mask[b * TT + i];
  __shared__ int r[256];
  r[tid] = s; __syncthreads();
  for (int st = 128; st > 0; st >>= 1) {
    if (tid < st) r[tid] += r[tid + st];
    __syncthreads();
  }
  if (tid == 0) { len[b] = r[0]; if (b == 0) *cnt = 0u; }
}

__global__ __launch_bounds__(256, 1) void elmo_lstm(
    const float* __restrict__ xin,
    const float* __restrict__ Wi_g, const float* __restrict__ Ws_g,
    const float* __restrict__ bs_g, const float* __restrict__ Wp_g,
    float* __restrict__ out,
    unsigned* __restrict__ cnt, const int* __restrict__ len_g,
    bf16_t* __restrict__ P, bf16_t* __restrict__ hbuf) {
  const int g    = blockIdx.x;
  const int tid  = threadIdx.x;
  const int hg   = g >> 7;        // batch half (0/1)
  const int wgi  = g & 127;
  const int cb   = wgi * 32;      // cell base
  const int wv   = tid >> 6;      // wave = gate index
  const int lane = tid & 63;
  const int lm   = lane & 15;
  const int lq   = lane >> 4;
  const int pb   = wgi * 4;       // owned h-column base (reduce phase)

  __shared__ bf16_t xh[16][1032];      // [n][k], stride 1032 (16B aligned rows)
  __shared__ float  gbuf[4][32][17];   // [gate][cell][n]
  __shared__ float  cbuf[32][17];      // persistent c-state [cell][n]
  __shared__ bf16_t abuf[16][48];      // act [n][cell]
  __shared__ bf16_t pbuf[512][16];     // partial h [p][n]
  __shared__ float  rbuf[64][5];
  __shared__ int    lenl[16];

  if (tid < 16) lenl[tid] = len_g[hg * 16 + tid];

  unsigned bark = 0;

#pragma unroll 1
  for (int l = 0; l < 2; ++l) {
    const float* WiL = Wi_g + (size_t)l * CC * 4 * HH;
    const float* WsL = Ws_g + (size_t)l * CC * 4 * HH;
    const float* bsL = bs_g + (size_t)l * CC * 4;
    const float* WpL = Wp_g + (size_t)l * HH * CC;

    // ---- layer init: weights -> registers (A-fragments) ----
    bf16x8 wfrag[64];                 // [mt*32+ks]; 256 VGPRs
#pragma unroll
    for (int mt = 0; mt < 2; ++mt) {
      const int row = wv * 4096 + cb + mt * 16 + lm;
#pragma unroll
      for (int ks = 0; ks < 32; ++ks) {
        const int k = ks * 32 + lq * 8;
        const float* src = (k < HH) ? (WiL + (size_t)row * HH + k)
                                    : (WsL + (size_t)row * HH + (k - HH));
        float4 a = ((const float4*)src)[0];
        float4 b = ((const float4*)src)[1];
        bf16x8 f;
        f[0] = (bf16_t)a.x; f[1] = (bf16_t)a.y; f[2] = (bf16_t)a.z; f[3] = (bf16_t)a.w;
        f[4] = (bf16_t)b.x; f[5] = (bf16_t)b.y; f[6] = (bf16_t)b.z; f[7] = (bf16_t)b.w;
        wfrag[mt * 32 + ks] = f;
      }
    }
    float biasv[8];
#pragma unroll
    for (int mt = 0; mt < 2; ++mt)
#pragma unroll
      for (int r = 0; r < 4; ++r)
        biasv[mt * 4 + r] = bsL[wv * 4096 + cb + mt * 16 + lq * 4 + r];

    bf16x8 pfrag[8];                  // Wp slice: rows wv*128+pt*16+lm, cols cb+lq*8..
#pragma unroll
    for (int pt = 0; pt < 8; ++pt) {
      const float* src = WpL + (size_t)(wv * 128 + pt * 16 + lm) * CC + cb + lq * 8;
      float4 a = ((const float4*)src)[0];
      float4 b = ((const float4*)src)[1];
      bf16x8 f;
      f[0] = (bf16_t)a.x; f[1] = (bf16_t)a.y; f[2] = (bf16_t)a.z; f[3] = (bf16_t)a.w;
      f[4] = (bf16_t)b.x; f[5] = (bf16_t)b.y; f[6] = (bf16_t)b.z; f[7] = (bf16_t)b.w;
      pfrag[pt] = f;
    }

    for (int i = tid; i < 32 * 17; i += 256) (&cbuf[0][0])[i] = 0.f;
    if (tid < 64) {                   // zero owned h slice
      int p = pb + (tid >> 4), n = tid & 15;
      hbuf[(size_t)(hg * 16 + n) * HH + p] = (bf16_t)0.f;
    }
    gridbar(cnt, 256u * (++bark));

    const float* xsrc = (l == 0) ? xin : out;   // layer2 input = layer1 out (fp32 in d_out)

#pragma unroll 1
    for (int t = 0; t < TT; ++t) {
      // ---- stage [x_t ; h_{t-1}] into LDS as bf16 ----
      {
        const int n = tid >> 4;
        const int co = (tid & 15) * 32;
        const float* xs = xsrc + ((size_t)(hg * 16 + n) * TT + t) * HH + co;
#pragma unroll
        for (int i = 0; i < 8; ++i) {
          float4 v = ((const float4*)xs)[i];
          bf16x4 pv = { (bf16_t)v.x, (bf16_t)v.y, (bf16_t)v.z, (bf16_t)v.w };
          *(bf16x4*)&xh[n][co + i * 4] = pv;
        }
        const int4* hs = (const int4*)(hbuf + (size_t)(hg * 16 + n) * HH + co);
#pragma unroll
        for (int i = 0; i < 4; ++i)
          *(int4*)&xh[n][HH + co + i * 8] = hs[i];
      }
      __syncthreads();

      // ---- gate GEMM: 64 MFMAs, weights from registers ----
      f32x4 acc0 = { biasv[0], biasv[1], biasv[2], biasv[3] };
      f32x4 acc1 = { biasv[4], biasv[5], biasv[6], biasv[7] };
#pragma unroll
      for (int ks = 0; ks < 32; ++ks) {
        bf16x8 bfr = *(const bf16x8*)&xh[lm][ks * 32 + lq * 8];
        acc0 = __builtin_amdgcn_mfma_f32_16x16x32_bf16(wfrag[ks],      bfr, acc0, 0, 0, 0);
        acc1 = __builtin_amdgcn_mfma_f32_16x16x32_bf16(wfrag[32 + ks], bfr, acc1, 0, 0, 0);
      }
#pragma unroll
      for (int r = 0; r < 4; ++r) {
        gbuf[wv][lq * 4 + r][lm]      = acc0[r];
        gbuf[wv][16 + lq * 4 + r][lm] = acc1[r];
      }
      __syncthreads();

      // ---- elementwise LSTM cell (2 (cell,n) pairs / thread) ----
#pragma unroll
      for (int e = 0; e < 2; ++e) {
        const int pp = tid * 2 + e;
        const int cell = pp >> 4, n = pp & 15;
        float ig = gbuf[0][cell][n], fg = gbuf[1][cell][n];
        float mg = gbuf[2][cell][n], og = gbuf[3][cell][n];
        float iv = fsigm(ig), fv = fsigm(fg), gv = ftanh(mg), ov = fsigm(og);
        float cp = cbuf[cell][n];
        float c  = fminf(fmaxf(iv * gv + fv * cp, -3.f), 3.f);
        const bool valid = t < lenl[n];
        float cn = valid ? c : cp;
        cbuf[cell][n] = cn;
        abuf[n][cell] = (bf16_t)(ov * ftanh(c));
        if (t == lenl[n] - 1)
          out[OUT_FC + ((size_t)(l * 32 + hg * 16 + n)) * CC + cb + cell] = cn;
      }
      __syncthreads();

      // ---- partial projection over own 32 cells ----
      {
        bf16x8 bfr = *(const bf16x8*)&abuf[lm][lq * 8];
#pragma unroll
        for (int pt = 0; pt < 8; ++pt) {
          f32x4 pa = { 0.f, 0.f, 0.f, 0.f };
          pa = __builtin_amdgcn_mfma_f32_16x16x32_bf16(pfrag[pt], bfr, pa, 0, 0, 0);
#pragma unroll
          for (int r = 0; r < 4; ++r)
            pbuf[wv * 128 + pt * 16 + lq * 4 + r][lm] = (bf16_t)pa[r];
        }
      }
      __syncthreads();
      {
        const int4* sp = (const int4*)(&pbuf[0][0]);
        int4* dp = (int4*)(P + (size_t)(hg * 128 + wgi) * (512 * 16));
#pragma unroll
        for (int i = 0; i < 4; ++i)
          dp[tid + 256 * i] = sp[tid + 256 * i];
      }
      gridbar(cnt, 256u * (++bark));

      // ---- reduce 128 partials for owned 4 h-columns ----
      {
        const int s = tid >> 6, o = tid & 63;
        const int p = pb + (o >> 4), n = o & 15;
        float sum = 0.f;
#pragma unroll 8
        for (int w2 = s * 32; w2 < s * 32 + 32; ++w2)
          sum += (float)P[((size_t)(hg * 128 + w2) * 512 + p) * 16 + n];
        rbuf[o][s] = sum;
      }
      __syncthreads();
      if (tid < 64) {
        const int o = tid;
        const int p = pb + (o >> 4), n = o & 15;
        const int b = hg * 16 + n;
        float h = rbuf[o][0] + rbuf[o][1] + rbuf[o][2] + rbuf[o][3];
        h = fminf(fmaxf(h, -3.f), 3.f);
        const bool valid = t < lenl[n];
        float hp = (float)hbuf[(size_t)b * HH + p];
        float hn = valid ? h : hp;
        hbuf[(size_t)b * HH + p] = (bf16_t)hn;
        float outv = valid ? h : 0.f;
        size_t oi = ((size_t)b * TT + t) * HH + p;
        if (l == 0) out[oi] = outv;      // layer-1 sequence (read back as layer-2 input)
        else        out[oi] += outv;     // residual: returned = l2_out + l1_out
        if (t == lenl[n] - 1)
          out[OUT_FH + ((size_t)(l * 32 + b)) * HH + p] = hn;
      }
      gridbar(cnt, 256u * (++bark));
    }
  }
}

extern "C" void kernel_launch(void* const* d_in, const int* in_sizes, int n_in,
                              void* d_out, int out_size, void* d_ws, size_t ws_size,
                              hipStream_t stream) {
  const float* xin = (const float*)d_in[0];
  const int*   mask = (const int*)d_in[1];
  const float* Wi  = (const float*)d_in[2];
  const float* Ws  = (const float*)d_in[3];
  const float* bs  = (const float*)d_in[4];
  const float* Wp  = (const float*)d_in[5];
  float* out = (float*)d_out;
  char* ws = (char*)d_ws;

  unsigned* cnt = (unsigned*)(ws);
  int* len      = (int*)(ws + 64);
  bf16_t* P    = (bf16_t*)(ws + 1024);                       // 2*128*512*16 bf16 = 4 MB
  bf16_t* hbuf = (bf16_t*)(ws + 1024 + (size_t)2 * 128 * 512 * 16 * 2);

  prep<<<32, 256, 0, stream>>>(mask, len, cnt);
  elmo_lstm<<<256, 256, 0, stream>>>(xin, Wi, Ws, bs, Wp, out, cnt, len, P, hbuf);
}